// Round 5
// baseline (272.805 us; speedup 1.0000x reference)
//
#include <hip/hip_runtime.h>
#include <hip/hip_bf16.h>

// Batched COO SpMM: out[k, row[e], f] = sum_e values[k][e] * b[k][col[e]][f]
// B=4, NNZ=800000, M=N=50000, F=64.
//
// Round 5: spmm lane remap. lane -> (batch k = lane>>4, feature quad
// f0 = (lane&15)*4). One global_load_dwordx4 per lane per edge covers all
// 4 batch planes (4*256B = 1KB per wave-edge in ONE VMEM instruction,
// was 4-8 dword gathers). Output store becomes one dwordx4. Unroll 4.
// Preprocessing identical to round 4 (proven, ~154us).

#define FEAT 64
#define SCAN_CHUNK 1024   // counts per scan block (256 threads x int4)

// ---------- preprocessing ----------

__global__ void hist_kernel(const int* __restrict__ rows,
                            int* __restrict__ counts, int nnz) {
    int i = blockIdx.x * blockDim.x + threadIdx.x;
    const int stride = gridDim.x * blockDim.x;
    for (; i < nnz; i += stride) atomicAdd(&counts[rows[i]], 1);
}

// S1: per-block sum of a 1024-count chunk (coalesced int4 reads).
__global__ __launch_bounds__(256) void scan_partial_kernel(
    const int* __restrict__ counts, int* __restrict__ blocksum, int m) {
    __shared__ int red[256];
    const int t = threadIdx.x;
    const int g = blockIdx.x * SCAN_CHUNK + t * 4;
    int s = 0;
    if (g + 3 < m) {
        const int4 c = *(const int4*)&counts[g];
        s = c.x + c.y + c.z + c.w;
    } else {
        for (int i = g; i < m; ++i) s += counts[i];
    }
    red[t] = s;
    __syncthreads();
    for (int off = 128; off; off >>= 1) {
        if (t < off) red[t] += red[t + off];
        __syncthreads();
    }
    if (t == 0) blocksum[blockIdx.x] = red[0];
}

// S2: single block scans the (<=256) block sums -> exclusive block offsets.
__global__ __launch_bounds__(256) void scan_block_kernel(
    const int* __restrict__ blocksum, int* __restrict__ blockoff,
    int nblk, int* __restrict__ row_ptr, int m, int nnz) {
    __shared__ int bufA[256];
    __shared__ int bufB[256];
    const int t = threadIdx.x;
    const int v = (t < nblk) ? blocksum[t] : 0;
    bufA[t] = v;
    __syncthreads();
    int* src = bufA;
    int* dst = bufB;
    for (int off = 1; off < 256; off <<= 1) {
        int x = src[t];
        if (t >= off) x += src[t - off];
        dst[t] = x;
        __syncthreads();
        int* tmp = src; src = dst; dst = tmp;
    }
    if (t < nblk) blockoff[t] = src[t] - v;   // exclusive
    if (t == 0) row_ptr[m] = nnz;
}

// S3: per-block LDS scan of its chunk + block offset -> row_ptr & cursor.
__global__ __launch_bounds__(256) void scan_apply_kernel(
    const int* __restrict__ counts, const int* __restrict__ blockoff,
    int* __restrict__ row_ptr, int* __restrict__ cursor, int m) {
    __shared__ int bufA[256];
    __shared__ int bufB[256];
    const int t = threadIdx.x;
    const int g = blockIdx.x * SCAN_CHUNK + t * 4;
    int c0 = 0, c1 = 0, c2 = 0, c3 = 0;
    if (g + 3 < m) {
        const int4 c = *(const int4*)&counts[g];
        c0 = c.x; c1 = c.y; c2 = c.z; c3 = c.w;
    } else {
        if (g < m)     c0 = counts[g];
        if (g + 1 < m) c1 = counts[g + 1];
        if (g + 2 < m) c2 = counts[g + 2];
    }
    const int s = c0 + c1 + c2 + c3;
    bufA[t] = s;
    __syncthreads();
    int* src = bufA;
    int* dst = bufB;
    for (int off = 1; off < 256; off <<= 1) {
        int x = src[t];
        if (t >= off) x += src[t - off];
        dst[t] = x;
        __syncthreads();
        int* tmp = src; src = dst; dst = tmp;
    }
    const int base = src[t] - s + blockoff[blockIdx.x];
    const int p0 = base, p1 = p0 + c0, p2 = p1 + c1, p3 = p2 + c2;
    if (g + 3 < m) {
        const int4 p = make_int4(p0, p1, p2, p3);
        *(int4*)&row_ptr[g] = p;
        *(int4*)&cursor[g]  = p;
    } else {
        if (g < m)     { row_ptr[g]     = p0; cursor[g]     = p0; }
        if (g + 1 < m) { row_ptr[g + 1] = p1; cursor[g + 1] = p1; }
        if (g + 2 < m) { row_ptr[g + 2] = p2; cursor[g + 2] = p2; }
    }
}

// Counting sort: scatter ONE int2 (col, edge_id) per edge.
__global__ void permute_kernel(const int* __restrict__ indices,
                               int* __restrict__ cursor,
                               int2* __restrict__ col_eid, int nnz) {
    int i = blockIdx.x * blockDim.x + threadIdx.x;
    const int stride = gridDim.x * blockDim.x;
    for (; i < nnz; i += stride) {
        const int r = indices[i];
        const int c = indices[nnz + i];
        const int pos = atomicAdd(&cursor[r], 1);
        col_eid[pos] = make_int2(c, i);
    }
}

// Gather values into sorted order: random READS (cache-friendly), coalesced
// 16B writes.
__global__ void valgather_kernel(const int2* __restrict__ col_eid,
                                 const float* __restrict__ values,
                                 float4* __restrict__ val4, int nnz) {
    int i = blockIdx.x * blockDim.x + threadIdx.x;
    const int stride = gridDim.x * blockDim.x;
    for (; i < nnz; i += stride) {
        const int e = col_eid[i].y;
        float4 v;
        v.x = values[e];
        v.y = values[(size_t)nnz + e];
        v.z = values[2 * (size_t)nnz + e];
        v.w = values[3 * (size_t)nnz + e];
        val4[i] = v;
    }
}

// ---------- main SpMM ----------
// One wave per row. lane -> (k = lane>>4, f0 = (lane&15)*4).
// Per edge: one dwordx4 gather per lane covers all 4 batch planes.
__global__ __launch_bounds__(256) void spmm_csr_kernel(
    const int* __restrict__ row_ptr, const int2* __restrict__ col_eid,
    const float4* __restrict__ val4, const float* __restrict__ b,
    float* __restrict__ out, int m) {
    const int lane = threadIdx.x & 63;
    const int wave = blockIdx.x * (blockDim.x >> 6) + (threadIdx.x >> 6);
    if (wave >= m) return;
    const int row   = wave;
    const int start = row_ptr[row];
    const int end   = row_ptr[row + 1];

    const int k  = lane >> 4;          // batch plane
    const int f0 = (lane & 15) * 4;    // feature quad
    const size_t bm = (size_t)m * FEAT;
    const float* __restrict__ bk = b + (size_t)k * bm + f0;  // + c*FEAT per edge

    float4 acc = make_float4(0.f, 0.f, 0.f, 0.f);
    int j = start;
    for (; j + 3 < end; j += 4) {
        const int2 ce0 = col_eid[j];
        const int2 ce1 = col_eid[j + 1];
        const int2 ce2 = col_eid[j + 2];
        const int2 ce3 = col_eid[j + 3];
        const float4 w0 = val4[j];
        const float4 w1 = val4[j + 1];
        const float4 w2 = val4[j + 2];
        const float4 w3 = val4[j + 3];
        const float4 b0 = *(const float4*)(bk + (size_t)ce0.x * FEAT);
        const float4 b1 = *(const float4*)(bk + (size_t)ce1.x * FEAT);
        const float4 b2 = *(const float4*)(bk + (size_t)ce2.x * FEAT);
        const float4 b3 = *(const float4*)(bk + (size_t)ce3.x * FEAT);
        // select this lane's batch value (k is per-lane constant -> 3 cndmask)
        const float v0 = (k == 0) ? w0.x : (k == 1) ? w0.y : (k == 2) ? w0.z : w0.w;
        const float v1 = (k == 0) ? w1.x : (k == 1) ? w1.y : (k == 2) ? w1.z : w1.w;
        const float v2 = (k == 0) ? w2.x : (k == 1) ? w2.y : (k == 2) ? w2.z : w2.w;
        const float v3 = (k == 0) ? w3.x : (k == 1) ? w3.y : (k == 2) ? w3.z : w3.w;
        acc.x += v0 * b0.x + v1 * b1.x + v2 * b2.x + v3 * b3.x;
        acc.y += v0 * b0.y + v1 * b1.y + v2 * b2.y + v3 * b3.y;
        acc.z += v0 * b0.z + v1 * b1.z + v2 * b2.z + v3 * b3.z;
        acc.w += v0 * b0.w + v1 * b1.w + v2 * b2.w + v3 * b3.w;
    }
    for (; j < end; ++j) {
        const int2 ce = col_eid[j];
        const float4 w = val4[j];
        const float4 bv = *(const float4*)(bk + (size_t)ce.x * FEAT);
        const float v = (k == 0) ? w.x : (k == 1) ? w.y : (k == 2) ? w.z : w.w;
        acc.x += v * bv.x;
        acc.y += v * bv.y;
        acc.z += v * bv.z;
        acc.w += v * bv.w;
    }
    *(float4*)(out + (size_t)k * bm + (size_t)row * FEAT + f0) = acc;
}

// ---------- fallback (round-1 atomic version) ----------
__global__ __launch_bounds__(256) void spmm_atomic_kernel(
    const int* __restrict__ indices, const float* __restrict__ values,
    const float* __restrict__ b, float* __restrict__ out,
    int nnz, int m, int batch, int ntasks) {
    const int lane = threadIdx.x & 63;
    const int waves_per_block = blockDim.x >> 6;
    const int nwaves = gridDim.x * waves_per_block;
    int wave = blockIdx.x * waves_per_block + (threadIdx.x >> 6);
    for (int task = wave; task < ntasks; task += nwaves) {
        const int e = task / batch;
        const int k = task - e * batch;
        const int row = indices[e];
        const int col = indices[nnz + e];
        const float v = values[(size_t)k * nnz + e];
        const float contrib = v * b[((size_t)k * m + col) * FEAT + lane];
        unsafeAtomicAdd(&out[((size_t)k * m + row) * FEAT + lane], contrib);
    }
}

static inline uintptr_t align16(uintptr_t p) { return (p + 15) & ~(uintptr_t)15; }

extern "C" void kernel_launch(void* const* d_in, const int* in_sizes, int n_in,
                              void* d_out, int out_size, void* d_ws, size_t ws_size,
                              hipStream_t stream) {
    const int* indices  = (const int*)d_in[0];    // [2, nnz]
    const float* values = (const float*)d_in[1];  // [batch, nnz]
    const float* b      = (const float*)d_in[4];  // [batch, m, FEAT]
    float* out          = (float*)d_out;

    const int nnz   = in_sizes[0] / 2;
    const int batch = in_sizes[1] / nnz;
    const int m     = out_size / (batch * FEAT);
    const int nblk  = (m + SCAN_CHUNK - 1) / SCAN_CHUNK;

    // ws layout, each array 16B-aligned:
    uintptr_t p = (uintptr_t)d_ws;
    int* counts      = (int*)align16(p);             p = (uintptr_t)(counts + m);
    int* row_ptr     = (int*)align16(p);             p = (uintptr_t)(row_ptr + m + 1);
    int* cursor      = (int*)align16(p);             p = (uintptr_t)(cursor + m);
    int* blocksum    = (int*)align16(p);             p = (uintptr_t)(blocksum + nblk);
    int* blockoff    = (int*)align16(p);             p = (uintptr_t)(blockoff + nblk);
    int2* col_eid    = (int2*)align16(p);            p = (uintptr_t)(col_eid + nnz);
    float4* val4     = (float4*)align16(p);          p = (uintptr_t)(val4 + nnz);
    const size_t need = p - (uintptr_t)d_ws;

    if (batch != 4 || nblk > 256 || ws_size < need) {
        hipMemsetAsync(d_out, 0, (size_t)out_size * sizeof(float), stream);
        spmm_atomic_kernel<<<2048, 256, 0, stream>>>(indices, values, b, out,
                                                     nnz, m, batch, nnz * batch);
        return;
    }

    hipMemsetAsync(counts, 0, (size_t)m * sizeof(int), stream);
    hist_kernel<<<1024, 256, 0, stream>>>(indices, counts, nnz);
    scan_partial_kernel<<<nblk, 256, 0, stream>>>(counts, blocksum, m);
    scan_block_kernel<<<1, 256, 0, stream>>>(blocksum, blockoff, nblk,
                                             row_ptr, m, nnz);
    scan_apply_kernel<<<nblk, 256, 0, stream>>>(counts, blockoff,
                                                row_ptr, cursor, m);
    permute_kernel<<<1024, 256, 0, stream>>>(indices, cursor, col_eid, nnz);
    valgather_kernel<<<1024, 256, 0, stream>>>(col_eid, values, val4, nnz);

    const int waves_per_block = 4;  // 256 threads
    const int grid = (m + waves_per_block - 1) / waves_per_block;
    spmm_csr_kernel<<<grid, 256, 0, stream>>>(row_ptr, col_eid, val4,
                                              b, out, m);
}

// Round 6
// 228.337 us; speedup vs baseline: 1.1947x; 1.1947x over previous
//
#include <hip/hip_runtime.h>
#include <hip/hip_bf16.h>

// Batched COO SpMM: out[k, row[e], f] = sum_e values[k][e] * b[k][col[e]][f]
// B=4, NNZ=800000, M=N=50000, F=64.
//
// Round 6: prep consolidation. Fused permute reads values COALESCED (planar
// streams) and scatters col (4B) + val4 (16B) = 2 random lines/edge, killing
// the valgather pass (which cost 4 random value-line reads per edge).
// Hierarchical scan from R4. SpMM from R5 (lane remap: k=lane>>4,
// f0=(lane&15)*4, one dwordx4 gather covers all 4 batch planes; proven
// memory-pattern-bound at ~118us).

#define FEAT 64
#define SCAN_CHUNK 1024   // counts per scan block (256 threads x int4)

// ---------- preprocessing ----------

__global__ void hist_kernel(const int* __restrict__ rows,
                            int* __restrict__ counts, int nnz) {
    int i = blockIdx.x * blockDim.x + threadIdx.x;
    const int stride = gridDim.x * blockDim.x;
    for (; i < nnz; i += stride) atomicAdd(&counts[rows[i]], 1);
}

// S1: per-block sum of a 1024-count chunk (coalesced int4 reads).
__global__ __launch_bounds__(256) void scan_partial_kernel(
    const int* __restrict__ counts, int* __restrict__ blocksum, int m) {
    __shared__ int red[256];
    const int t = threadIdx.x;
    const int g = blockIdx.x * SCAN_CHUNK + t * 4;
    int s = 0;
    if (g + 3 < m) {
        const int4 c = *(const int4*)&counts[g];
        s = c.x + c.y + c.z + c.w;
    } else {
        for (int i = g; i < m; ++i) s += counts[i];
    }
    red[t] = s;
    __syncthreads();
    for (int off = 128; off; off >>= 1) {
        if (t < off) red[t] += red[t + off];
        __syncthreads();
    }
    if (t == 0) blocksum[blockIdx.x] = red[0];
}

// S2: single block scans the (<=256) block sums -> exclusive block offsets.
__global__ __launch_bounds__(256) void scan_block_kernel(
    const int* __restrict__ blocksum, int* __restrict__ blockoff,
    int nblk, int* __restrict__ row_ptr, int m, int nnz) {
    __shared__ int bufA[256];
    __shared__ int bufB[256];
    const int t = threadIdx.x;
    const int v = (t < nblk) ? blocksum[t] : 0;
    bufA[t] = v;
    __syncthreads();
    int* src = bufA;
    int* dst = bufB;
    for (int off = 1; off < 256; off <<= 1) {
        int x = src[t];
        if (t >= off) x += src[t - off];
        dst[t] = x;
        __syncthreads();
        int* tmp = src; src = dst; dst = tmp;
    }
    if (t < nblk) blockoff[t] = src[t] - v;   // exclusive
    if (t == 0) row_ptr[m] = nnz;
}

// S3: per-block LDS scan of its chunk + block offset -> row_ptr & cursor.
__global__ __launch_bounds__(256) void scan_apply_kernel(
    const int* __restrict__ counts, const int* __restrict__ blockoff,
    int* __restrict__ row_ptr, int* __restrict__ cursor, int m) {
    __shared__ int bufA[256];
    __shared__ int bufB[256];
    const int t = threadIdx.x;
    const int g = blockIdx.x * SCAN_CHUNK + t * 4;
    int c0 = 0, c1 = 0, c2 = 0, c3 = 0;
    if (g + 3 < m) {
        const int4 c = *(const int4*)&counts[g];
        c0 = c.x; c1 = c.y; c2 = c.z; c3 = c.w;
    } else {
        if (g < m)     c0 = counts[g];
        if (g + 1 < m) c1 = counts[g + 1];
        if (g + 2 < m) c2 = counts[g + 2];
    }
    const int s = c0 + c1 + c2 + c3;
    bufA[t] = s;
    __syncthreads();
    int* src = bufA;
    int* dst = bufB;
    for (int off = 1; off < 256; off <<= 1) {
        int x = src[t];
        if (t >= off) x += src[t - off];
        dst[t] = x;
        __syncthreads();
        int* tmp = src; src = dst; dst = tmp;
    }
    const int base = src[t] - s + blockoff[blockIdx.x];
    const int p0 = base, p1 = p0 + c0, p2 = p1 + c1, p3 = p2 + c2;
    if (g + 3 < m) {
        const int4 p = make_int4(p0, p1, p2, p3);
        *(int4*)&row_ptr[g] = p;
        *(int4*)&cursor[g]  = p;
    } else {
        if (g < m)     { row_ptr[g]     = p0; cursor[g]     = p0; }
        if (g + 1 < m) { row_ptr[g + 1] = p1; cursor[g + 1] = p1; }
        if (g + 2 < m) { row_ptr[g + 2] = p2; cursor[g + 2] = p2; }
    }
}

// Fused counting sort: read indices + 4 value planes COALESCED, scatter
// col (4B) + packed val4 (16B) -> 2 random lines per edge, no valgather.
__global__ void permute_fused_kernel(const int* __restrict__ indices,
                                     const float* __restrict__ values,
                                     int* __restrict__ cursor,
                                     int* __restrict__ col_sorted,
                                     float4* __restrict__ val4_sorted,
                                     int nnz) {
    int i = blockIdx.x * blockDim.x + threadIdx.x;
    const int stride = gridDim.x * blockDim.x;
    for (; i < nnz; i += stride) {
        const int r = indices[i];
        const int c = indices[nnz + i];
        float4 v;
        v.x = values[i];
        v.y = values[(size_t)nnz + i];
        v.z = values[2 * (size_t)nnz + i];
        v.w = values[3 * (size_t)nnz + i];
        const int pos = atomicAdd(&cursor[r], 1);
        col_sorted[pos] = c;
        val4_sorted[pos] = v;
    }
}

// ---------- main SpMM ----------
// One wave per row. lane -> (k = lane>>4, f0 = (lane&15)*4).
// Per edge: one dwordx4 gather per lane covers all 4 batch planes.
__global__ __launch_bounds__(256) void spmm_csr_kernel(
    const int* __restrict__ row_ptr, const int* __restrict__ col_sorted,
    const float4* __restrict__ val4, const float* __restrict__ b,
    float* __restrict__ out, int m) {
    const int lane = threadIdx.x & 63;
    const int wave = blockIdx.x * (blockDim.x >> 6) + (threadIdx.x >> 6);
    if (wave >= m) return;
    const int row   = wave;
    const int start = row_ptr[row];
    const int end   = row_ptr[row + 1];

    const int k  = lane >> 4;          // batch plane
    const int f0 = (lane & 15) * 4;    // feature quad
    const size_t bm = (size_t)m * FEAT;
    const float* __restrict__ bk = b + (size_t)k * bm + f0;  // + c*FEAT per edge

    float4 acc = make_float4(0.f, 0.f, 0.f, 0.f);
    int j = start;
    for (; j + 3 < end; j += 4) {
        const int c0 = col_sorted[j];
        const int c1 = col_sorted[j + 1];
        const int c2 = col_sorted[j + 2];
        const int c3 = col_sorted[j + 3];
        const float4 w0 = val4[j];
        const float4 w1 = val4[j + 1];
        const float4 w2 = val4[j + 2];
        const float4 w3 = val4[j + 3];
        const float4 b0 = *(const float4*)(bk + (size_t)c0 * FEAT);
        const float4 b1 = *(const float4*)(bk + (size_t)c1 * FEAT);
        const float4 b2 = *(const float4*)(bk + (size_t)c2 * FEAT);
        const float4 b3 = *(const float4*)(bk + (size_t)c3 * FEAT);
        const float v0 = (k == 0) ? w0.x : (k == 1) ? w0.y : (k == 2) ? w0.z : w0.w;
        const float v1 = (k == 0) ? w1.x : (k == 1) ? w1.y : (k == 2) ? w1.z : w1.w;
        const float v2 = (k == 0) ? w2.x : (k == 1) ? w2.y : (k == 2) ? w2.z : w2.w;
        const float v3 = (k == 0) ? w3.x : (k == 1) ? w3.y : (k == 2) ? w3.z : w3.w;
        acc.x += v0 * b0.x + v1 * b1.x + v2 * b2.x + v3 * b3.x;
        acc.y += v0 * b0.y + v1 * b1.y + v2 * b2.y + v3 * b3.y;
        acc.z += v0 * b0.z + v1 * b1.z + v2 * b2.z + v3 * b3.z;
        acc.w += v0 * b0.w + v1 * b1.w + v2 * b2.w + v3 * b3.w;
    }
    for (; j < end; ++j) {
        const int c = col_sorted[j];
        const float4 w = val4[j];
        const float4 bv = *(const float4*)(bk + (size_t)c * FEAT);
        const float v = (k == 0) ? w.x : (k == 1) ? w.y : (k == 2) ? w.z : w.w;
        acc.x += v * bv.x;
        acc.y += v * bv.y;
        acc.z += v * bv.z;
        acc.w += v * bv.w;
    }
    *(float4*)(out + (size_t)k * bm + (size_t)row * FEAT + f0) = acc;
}

// ---------- fallback (round-1 atomic version) ----------
__global__ __launch_bounds__(256) void spmm_atomic_kernel(
    const int* __restrict__ indices, const float* __restrict__ values,
    const float* __restrict__ b, float* __restrict__ out,
    int nnz, int m, int batch, int ntasks) {
    const int lane = threadIdx.x & 63;
    const int waves_per_block = blockDim.x >> 6;
    const int nwaves = gridDim.x * waves_per_block;
    int wave = blockIdx.x * waves_per_block + (threadIdx.x >> 6);
    for (int task = wave; task < ntasks; task += nwaves) {
        const int e = task / batch;
        const int k = task - e * batch;
        const int row = indices[e];
        const int col = indices[nnz + e];
        const float v = values[(size_t)k * nnz + e];
        const float contrib = v * b[((size_t)k * m + col) * FEAT + lane];
        unsafeAtomicAdd(&out[((size_t)k * m + row) * FEAT + lane], contrib);
    }
}

static inline uintptr_t align16(uintptr_t p) { return (p + 15) & ~(uintptr_t)15; }

extern "C" void kernel_launch(void* const* d_in, const int* in_sizes, int n_in,
                              void* d_out, int out_size, void* d_ws, size_t ws_size,
                              hipStream_t stream) {
    const int* indices  = (const int*)d_in[0];    // [2, nnz]
    const float* values = (const float*)d_in[1];  // [batch, nnz]
    const float* b      = (const float*)d_in[4];  // [batch, m, FEAT]
    float* out          = (float*)d_out;

    const int nnz   = in_sizes[0] / 2;
    const int batch = in_sizes[1] / nnz;
    const int m     = out_size / (batch * FEAT);
    const int nblk  = (m + SCAN_CHUNK - 1) / SCAN_CHUNK;

    // ws layout, each array 16B-aligned:
    uintptr_t p = (uintptr_t)d_ws;
    int* counts      = (int*)align16(p);             p = (uintptr_t)(counts + m);
    int* row_ptr     = (int*)align16(p);             p = (uintptr_t)(row_ptr + m + 1);
    int* cursor      = (int*)align16(p);             p = (uintptr_t)(cursor + m);
    int* blocksum    = (int*)align16(p);             p = (uintptr_t)(blocksum + nblk);
    int* blockoff    = (int*)align16(p);             p = (uintptr_t)(blockoff + nblk);
    int* col_sorted  = (int*)align16(p);             p = (uintptr_t)(col_sorted + nnz);
    float4* val4     = (float4*)align16(p);          p = (uintptr_t)(val4 + nnz);
    const size_t need = p - (uintptr_t)d_ws;

    if (batch != 4 || nblk > 256 || ws_size < need) {
        hipMemsetAsync(d_out, 0, (size_t)out_size * sizeof(float), stream);
        spmm_atomic_kernel<<<2048, 256, 0, stream>>>(indices, values, b, out,
                                                     nnz, m, batch, nnz * batch);
        return;
    }

    hipMemsetAsync(counts, 0, (size_t)m * sizeof(int), stream);
    hist_kernel<<<1024, 256, 0, stream>>>(indices, counts, nnz);
    scan_partial_kernel<<<nblk, 256, 0, stream>>>(counts, blocksum, m);
    scan_block_kernel<<<1, 256, 0, stream>>>(blocksum, blockoff, nblk,
                                             row_ptr, m, nnz);
    scan_apply_kernel<<<nblk, 256, 0, stream>>>(counts, blockoff,
                                                row_ptr, cursor, m);
    permute_fused_kernel<<<1024, 256, 0, stream>>>(indices, values, cursor,
                                                   col_sorted, val4, nnz);

    const int waves_per_block = 4;  // 256 threads
    const int grid = (m + waves_per_block - 1) / waves_per_block;
    spmm_csr_kernel<<<grid, 256, 0, stream>>>(row_ptr, col_sorted, val4,
                                              b, out, m);
}

// Round 7
// 195.310 us; speedup vs baseline: 1.3968x; 1.1691x over previous
//
#include <hip/hip_runtime.h>
#include <hip/hip_bf16.h>

// Batched COO SpMM: out[k, row[e], f] = sum_e values[k][e] * b[k][col[e]][f]
// B=4, NNZ=800000, M=N=50000, F=64.
//
// Round 7: bf16 gather path. Prep converts b [4][m][64] fp32 -> b16 [m][4][64]
// bf16 (25.6MB): per edge the wave reads ONE contiguous 512B chunk instead of
// 4x256B fp32 -> halves L2-fill traffic (the proven spmm bottleneck) and
// halves the gather footprint. Transform is fused into the permute launch
// (independent streaming work rides the scatter kernel's idle bandwidth).
// Tolerance is 0.665 (bf16-floored); bf16 b adds ~0.1 worst-case error.

#define FEAT 64
#define SCAN_CHUNK 1024
#define PERM_BLOCKS 1024

__device__ inline unsigned short f2bf(float x) {
    unsigned u = __float_as_uint(x);
    unsigned r = (u + 0x7FFFu + ((u >> 16) & 1u)) >> 16;   // round-nearest-even
    return (unsigned short)r;
}

// ---------- preprocessing ----------

__global__ void hist_kernel(const int* __restrict__ rows,
                            int* __restrict__ counts, int nnz) {
    int i = blockIdx.x * blockDim.x + threadIdx.x;
    const int stride = gridDim.x * blockDim.x;
    for (; i < nnz; i += stride) atomicAdd(&counts[rows[i]], 1);
}

// S1: per-block sum of a 1024-count chunk (coalesced int4 reads).
__global__ __launch_bounds__(256) void scan_partial_kernel(
    const int* __restrict__ counts, int* __restrict__ blocksum, int m) {
    __shared__ int red[256];
    const int t = threadIdx.x;
    const int g = blockIdx.x * SCAN_CHUNK + t * 4;
    int s = 0;
    if (g + 3 < m) {
        const int4 c = *(const int4*)&counts[g];
        s = c.x + c.y + c.z + c.w;
    } else {
        for (int i = g; i < m; ++i) s += counts[i];
    }
    red[t] = s;
    __syncthreads();
    for (int off = 128; off; off >>= 1) {
        if (t < off) red[t] += red[t + off];
        __syncthreads();
    }
    if (t == 0) blocksum[blockIdx.x] = red[0];
}

// S2: single block scans the (<=256) block sums -> exclusive block offsets.
__global__ __launch_bounds__(256) void scan_block_kernel(
    const int* __restrict__ blocksum, int* __restrict__ blockoff,
    int nblk, int* __restrict__ row_ptr, int m, int nnz) {
    __shared__ int bufA[256];
    __shared__ int bufB[256];
    const int t = threadIdx.x;
    const int v = (t < nblk) ? blocksum[t] : 0;
    bufA[t] = v;
    __syncthreads();
    int* src = bufA;
    int* dst = bufB;
    for (int off = 1; off < 256; off <<= 1) {
        int x = src[t];
        if (t >= off) x += src[t - off];
        dst[t] = x;
        __syncthreads();
        int* tmp = src; src = dst; dst = tmp;
    }
    if (t < nblk) blockoff[t] = src[t] - v;   // exclusive
    if (t == 0) row_ptr[m] = nnz;
}

// S3: per-block LDS scan of its chunk + block offset -> row_ptr & cursor.
__global__ __launch_bounds__(256) void scan_apply_kernel(
    const int* __restrict__ counts, const int* __restrict__ blockoff,
    int* __restrict__ row_ptr, int* __restrict__ cursor, int m) {
    __shared__ int bufA[256];
    __shared__ int bufB[256];
    const int t = threadIdx.x;
    const int g = blockIdx.x * SCAN_CHUNK + t * 4;
    int c0 = 0, c1 = 0, c2 = 0, c3 = 0;
    if (g + 3 < m) {
        const int4 c = *(const int4*)&counts[g];
        c0 = c.x; c1 = c.y; c2 = c.z; c3 = c.w;
    } else {
        if (g < m)     c0 = counts[g];
        if (g + 1 < m) c1 = counts[g + 1];
        if (g + 2 < m) c2 = counts[g + 2];
    }
    const int s = c0 + c1 + c2 + c3;
    bufA[t] = s;
    __syncthreads();
    int* src = bufA;
    int* dst = bufB;
    for (int off = 1; off < 256; off <<= 1) {
        int x = src[t];
        if (t >= off) x += src[t - off];
        dst[t] = x;
        __syncthreads();
        int* tmp = src; src = dst; dst = tmp;
    }
    const int base = src[t] - s + blockoff[blockIdx.x];
    const int p0 = base, p1 = p0 + c0, p2 = p1 + c1, p3 = p2 + c2;
    if (g + 3 < m) {
        const int4 pq = make_int4(p0, p1, p2, p3);
        *(int4*)&row_ptr[g] = pq;
        *(int4*)&cursor[g]  = pq;
    } else {
        if (g < m)     { row_ptr[g]     = p0; cursor[g]     = p0; }
        if (g + 1 < m) { row_ptr[g + 1] = p1; cursor[g + 1] = p1; }
        if (g + 2 < m) { row_ptr[g + 2] = p2; cursor[g + 2] = p2; }
    }
}

// Fused: blocks [0,PERM_BLOCKS) do the counting-sort scatter (coalesced value
// reads, scatter col 4B + val4 16B). Blocks >= PERM_BLOCKS stream-convert
// b [4][m][64] fp32 -> b16 [m][4][64] bf16 (independent work, hides under
// the scatter's latency stalls).
__global__ void permute_transform_kernel(
    const int* __restrict__ indices, const float* __restrict__ values,
    int* __restrict__ cursor, int* __restrict__ col_sorted,
    float4* __restrict__ val4_sorted, int nnz,
    const float* __restrict__ b, unsigned short* __restrict__ b16, int m) {
    if (blockIdx.x < PERM_BLOCKS) {
        int i = blockIdx.x * blockDim.x + threadIdx.x;
        const int stride = PERM_BLOCKS * blockDim.x;
        for (; i < nnz; i += stride) {
            const int r = indices[i];
            const int c = indices[nnz + i];
            float4 v;
            v.x = values[i];
            v.y = values[(size_t)nnz + i];
            v.z = values[2 * (size_t)nnz + i];
            v.w = values[3 * (size_t)nnz + i];
            const int pos = atomicAdd(&cursor[r], 1);
            col_sorted[pos] = c;
            val4_sorted[pos] = v;
        }
    } else {
        // q indexes float4s of b: q in [0, 4*m*16)
        const int q = (blockIdx.x - PERM_BLOCKS) * blockDim.x + threadIdx.x;
        const int plane = m * 16;             // float4s per batch plane
        if (q < 4 * plane) {
            const float4 v = *(const float4*)(b + (size_t)q * 4);
            const int k   = q / plane;
            const int rem = q - k * plane;
            const int c   = rem >> 4;
            const int f0  = (rem & 15) * 4;
            ushort4 o;
            o.x = f2bf(v.x); o.y = f2bf(v.y); o.z = f2bf(v.z); o.w = f2bf(v.w);
            *(ushort4*)(b16 + (size_t)c * 256 + k * 64 + f0) = o;
        }
    }
}

// ---------- main SpMM (bf16 gather) ----------
// One wave per row. lane -> (k = lane>>4, f0 = (lane&15)*4).
// Per edge the wave reads ONE contiguous 512B chunk of b16[c].
__global__ __launch_bounds__(256) void spmm_csr_bf16_kernel(
    const int* __restrict__ row_ptr, const int* __restrict__ col_sorted,
    const float4* __restrict__ val4, const unsigned short* __restrict__ b16,
    float* __restrict__ out, int m) {
    const int lane = threadIdx.x & 63;
    const int wave = blockIdx.x * (blockDim.x >> 6) + (threadIdx.x >> 6);
    if (wave >= m) return;
    const int row   = wave;
    const int start = row_ptr[row];
    const int end   = row_ptr[row + 1];

    const int k  = lane >> 4;
    const int f0 = (lane & 15) * 4;
    const unsigned short* __restrict__ bk = b16 + k * 64 + f0;  // + c*256/edge

#define BF(u) __uint_as_float((unsigned)(u) << 16)
    float4 acc = make_float4(0.f, 0.f, 0.f, 0.f);
    int j = start;
    for (; j + 3 < end; j += 4) {
        const int c0 = col_sorted[j];
        const int c1 = col_sorted[j + 1];
        const int c2 = col_sorted[j + 2];
        const int c3 = col_sorted[j + 3];
        const float4 w0 = val4[j];
        const float4 w1 = val4[j + 1];
        const float4 w2 = val4[j + 2];
        const float4 w3 = val4[j + 3];
        const ushort4 u0 = *(const ushort4*)(bk + (size_t)c0 * 256);
        const ushort4 u1 = *(const ushort4*)(bk + (size_t)c1 * 256);
        const ushort4 u2 = *(const ushort4*)(bk + (size_t)c2 * 256);
        const ushort4 u3 = *(const ushort4*)(bk + (size_t)c3 * 256);
        const float v0 = (k == 0) ? w0.x : (k == 1) ? w0.y : (k == 2) ? w0.z : w0.w;
        const float v1 = (k == 0) ? w1.x : (k == 1) ? w1.y : (k == 2) ? w1.z : w1.w;
        const float v2 = (k == 0) ? w2.x : (k == 1) ? w2.y : (k == 2) ? w2.z : w2.w;
        const float v3 = (k == 0) ? w3.x : (k == 1) ? w3.y : (k == 2) ? w3.z : w3.w;
        acc.x += v0 * BF(u0.x) + v1 * BF(u1.x) + v2 * BF(u2.x) + v3 * BF(u3.x);
        acc.y += v0 * BF(u0.y) + v1 * BF(u1.y) + v2 * BF(u2.y) + v3 * BF(u3.y);
        acc.z += v0 * BF(u0.z) + v1 * BF(u1.z) + v2 * BF(u2.z) + v3 * BF(u3.z);
        acc.w += v0 * BF(u0.w) + v1 * BF(u1.w) + v2 * BF(u2.w) + v3 * BF(u3.w);
    }
    for (; j < end; ++j) {
        const int c = col_sorted[j];
        const float4 w = val4[j];
        const ushort4 u = *(const ushort4*)(bk + (size_t)c * 256);
        const float v = (k == 0) ? w.x : (k == 1) ? w.y : (k == 2) ? w.z : w.w;
        acc.x += v * BF(u.x);
        acc.y += v * BF(u.y);
        acc.z += v * BF(u.z);
        acc.w += v * BF(u.w);
    }
#undef BF
    const size_t bm = (size_t)m * FEAT;
    *(float4*)(out + (size_t)k * bm + (size_t)row * FEAT + f0) = acc;
}

// ---------- fp32 spmm (R6 path, used if ws can't hold b16) ----------
__global__ __launch_bounds__(256) void spmm_csr_kernel(
    const int* __restrict__ row_ptr, const int* __restrict__ col_sorted,
    const float4* __restrict__ val4, const float* __restrict__ b,
    float* __restrict__ out, int m) {
    const int lane = threadIdx.x & 63;
    const int wave = blockIdx.x * (blockDim.x >> 6) + (threadIdx.x >> 6);
    if (wave >= m) return;
    const int row   = wave;
    const int start = row_ptr[row];
    const int end   = row_ptr[row + 1];
    const int k  = lane >> 4;
    const int f0 = (lane & 15) * 4;
    const size_t bm = (size_t)m * FEAT;
    const float* __restrict__ bk = b + (size_t)k * bm + f0;
    float4 acc = make_float4(0.f, 0.f, 0.f, 0.f);
    for (int j = start; j < end; ++j) {
        const int c = col_sorted[j];
        const float4 w = val4[j];
        const float4 bv = *(const float4*)(bk + (size_t)c * FEAT);
        const float v = (k == 0) ? w.x : (k == 1) ? w.y : (k == 2) ? w.z : w.w;
        acc.x += v * bv.x;
        acc.y += v * bv.y;
        acc.z += v * bv.z;
        acc.w += v * bv.w;
    }
    *(float4*)(out + (size_t)k * bm + (size_t)row * FEAT + f0) = acc;
}

__global__ void permute_fused_kernel(const int* __restrict__ indices,
                                     const float* __restrict__ values,
                                     int* __restrict__ cursor,
                                     int* __restrict__ col_sorted,
                                     float4* __restrict__ val4_sorted,
                                     int nnz) {
    int i = blockIdx.x * blockDim.x + threadIdx.x;
    const int stride = gridDim.x * blockDim.x;
    for (; i < nnz; i += stride) {
        const int r = indices[i];
        const int c = indices[nnz + i];
        float4 v;
        v.x = values[i];
        v.y = values[(size_t)nnz + i];
        v.z = values[2 * (size_t)nnz + i];
        v.w = values[3 * (size_t)nnz + i];
        const int pos = atomicAdd(&cursor[r], 1);
        col_sorted[pos] = c;
        val4_sorted[pos] = v;
    }
}

// ---------- fallback (round-1 atomic version) ----------
__global__ __launch_bounds__(256) void spmm_atomic_kernel(
    const int* __restrict__ indices, const float* __restrict__ values,
    const float* __restrict__ b, float* __restrict__ out,
    int nnz, int m, int batch, int ntasks) {
    const int lane = threadIdx.x & 63;
    const int waves_per_block = blockDim.x >> 6;
    const int nwaves = gridDim.x * waves_per_block;
    int wave = blockIdx.x * waves_per_block + (threadIdx.x >> 6);
    for (int task = wave; task < ntasks; task += nwaves) {
        const int e = task / batch;
        const int k = task - e * batch;
        const int row = indices[e];
        const int col = indices[nnz + e];
        const float v = values[(size_t)k * nnz + e];
        const float contrib = v * b[((size_t)k * m + col) * FEAT + lane];
        unsafeAtomicAdd(&out[((size_t)k * m + row) * FEAT + lane], contrib);
    }
}

static inline uintptr_t align16(uintptr_t p) { return (p + 15) & ~(uintptr_t)15; }

extern "C" void kernel_launch(void* const* d_in, const int* in_sizes, int n_in,
                              void* d_out, int out_size, void* d_ws, size_t ws_size,
                              hipStream_t stream) {
    const int* indices  = (const int*)d_in[0];    // [2, nnz]
    const float* values = (const float*)d_in[1];  // [batch, nnz]
    const float* b      = (const float*)d_in[4];  // [batch, m, FEAT]
    float* out          = (float*)d_out;

    const int nnz   = in_sizes[0] / 2;
    const int batch = in_sizes[1] / nnz;
    const int m     = out_size / (batch * FEAT);
    const int nblk  = (m + SCAN_CHUNK - 1) / SCAN_CHUNK;

    // ws layout, each array 16B-aligned:
    uintptr_t p = (uintptr_t)d_ws;
    int* counts      = (int*)align16(p);             p = (uintptr_t)(counts + m);
    int* row_ptr     = (int*)align16(p);             p = (uintptr_t)(row_ptr + m + 1);
    int* cursor      = (int*)align16(p);             p = (uintptr_t)(cursor + m);
    int* blocksum    = (int*)align16(p);             p = (uintptr_t)(blocksum + nblk);
    int* blockoff    = (int*)align16(p);             p = (uintptr_t)(blockoff + nblk);
    int* col_sorted  = (int*)align16(p);             p = (uintptr_t)(col_sorted + nnz);
    float4* val4     = (float4*)align16(p);          p = (uintptr_t)(val4 + nnz);
    const size_t need_base = p - (uintptr_t)d_ws;
    unsigned short* b16 = (unsigned short*)align16(p);
    p = (uintptr_t)(b16 + (size_t)m * 4 * FEAT);
    const size_t need_b16 = p - (uintptr_t)d_ws;

    if (batch != 4 || nblk > 256 || ws_size < need_base) {
        hipMemsetAsync(d_out, 0, (size_t)out_size * sizeof(float), stream);
        spmm_atomic_kernel<<<2048, 256, 0, stream>>>(indices, values, b, out,
                                                     nnz, m, batch, nnz * batch);
        return;
    }

    hipMemsetAsync(counts, 0, (size_t)m * sizeof(int), stream);
    hist_kernel<<<1024, 256, 0, stream>>>(indices, counts, nnz);
    scan_partial_kernel<<<nblk, 256, 0, stream>>>(counts, blocksum, m);
    scan_block_kernel<<<1, 256, 0, stream>>>(blocksum, blockoff, nblk,
                                             row_ptr, m, nnz);
    scan_apply_kernel<<<nblk, 256, 0, stream>>>(counts, blockoff,
                                                row_ptr, cursor, m);

    const int waves_per_block = 4;  // 256 threads
    const int grid = (m + waves_per_block - 1) / waves_per_block;

    if (ws_size >= need_b16) {
        // main path: permute + b->bf16 transform fused, bf16 gather spmm
        const int tblocks = (m * FEAT + 255) / 256;   // float4s of b / 256
        permute_transform_kernel<<<PERM_BLOCKS + tblocks, 256, 0, stream>>>(
            indices, values, cursor, col_sorted, val4, nnz, b, b16, m);
        spmm_csr_bf16_kernel<<<grid, 256, 0, stream>>>(row_ptr, col_sorted,
                                                       val4, b16, out, m);
    } else {
        // R6 path (fp32 gather)
        permute_fused_kernel<<<PERM_BLOCKS, 256, 0, stream>>>(
            indices, values, cursor, col_sorted, val4, nnz);
        spmm_csr_kernel<<<grid, 256, 0, stream>>>(row_ptr, col_sorted, val4,
                                                  b, out, m);
    }
}

// Round 9
// 183.556 us; speedup vs baseline: 1.4862x; 1.0640x over previous
//
#include <hip/hip_runtime.h>
#include <hip/hip_bf16.h>

// Batched COO SpMM: out[k, row[e], f] = sum_e values[k][e] * b[k][col[e]][f]
// B=4, NNZ=800000, M=N=50000, F=64.
//
// Round 9 = Round 8 with the transform-coverage bug fixed: tblocks must span
// ALL of b (m*FEAT float4s), not m*16 (R8 left b16 planes k=1..3 poisoned).
// Design: single-scatter prep (one uint4 {col, bf16 v0|v1, bf16 v2|v3, 0}
// per edge), b->bf16 [m][4][64] transform rides the hist launch, spmm gathers
// one contiguous 512B b16 chunk per edge (proven 77us in R7).

#define FEAT 64
#define SCAN_CHUNK 1024
#define HIST_BLOCKS 1024
#define PERM_BLOCKS 1024

__device__ inline unsigned f2bf(float x) {
    unsigned u = __float_as_uint(x);
    return (u + 0x7FFFu + ((u >> 16) & 1u)) >> 16;   // round-nearest-even
}

// ---------- preprocessing ----------

// Fused: blocks [0,HIST_BLOCKS) histogram rows; blocks >= HIST_BLOCKS
// stream-convert b [4][m][64] fp32 -> b16 [m][4][64] bf16.
__global__ void hist_transform_kernel(const int* __restrict__ rows,
                                      int* __restrict__ counts, int nnz,
                                      const float* __restrict__ b,
                                      unsigned short* __restrict__ b16, int m) {
    if (blockIdx.x < HIST_BLOCKS) {
        int i = blockIdx.x * blockDim.x + threadIdx.x;
        const int stride = HIST_BLOCKS * blockDim.x;
        for (; i < nnz; i += stride) atomicAdd(&counts[rows[i]], 1);
    } else {
        const int q = (blockIdx.x - HIST_BLOCKS) * blockDim.x + threadIdx.x;
        const int plane = m * 16;             // float4s per batch plane
        if (q < 4 * plane) {
            const float4 v = *(const float4*)(b + (size_t)q * 4);
            const int k   = q / plane;
            const int rem = q - k * plane;
            const int c   = rem >> 4;
            const int f0  = (rem & 15) * 4;
            ushort4 o;
            o.x = (unsigned short)f2bf(v.x);
            o.y = (unsigned short)f2bf(v.y);
            o.z = (unsigned short)f2bf(v.z);
            o.w = (unsigned short)f2bf(v.w);
            *(ushort4*)(b16 + (size_t)c * 256 + k * 64 + f0) = o;
        }
    }
}

// S1: per-block sum of a 1024-count chunk (coalesced int4 reads).
__global__ __launch_bounds__(256) void scan_partial_kernel(
    const int* __restrict__ counts, int* __restrict__ blocksum, int m) {
    __shared__ int red[256];
    const int t = threadIdx.x;
    const int g = blockIdx.x * SCAN_CHUNK + t * 4;
    int s = 0;
    if (g + 3 < m) {
        const int4 c = *(const int4*)&counts[g];
        s = c.x + c.y + c.z + c.w;
    } else {
        for (int i = g; i < m; ++i) s += counts[i];
    }
    red[t] = s;
    __syncthreads();
    for (int off = 128; off; off >>= 1) {
        if (t < off) red[t] += red[t + off];
        __syncthreads();
    }
    if (t == 0) blocksum[blockIdx.x] = red[0];
}

// S2: single block scans the (<=256) block sums -> exclusive block offsets.
__global__ __launch_bounds__(256) void scan_block_kernel(
    const int* __restrict__ blocksum, int* __restrict__ blockoff,
    int nblk, int* __restrict__ row_ptr, int m, int nnz) {
    __shared__ int bufA[256];
    __shared__ int bufB[256];
    const int t = threadIdx.x;
    const int v = (t < nblk) ? blocksum[t] : 0;
    bufA[t] = v;
    __syncthreads();
    int* src = bufA;
    int* dst = bufB;
    for (int off = 1; off < 256; off <<= 1) {
        int x = src[t];
        if (t >= off) x += src[t - off];
        dst[t] = x;
        __syncthreads();
        int* tmp = src; src = dst; dst = tmp;
    }
    if (t < nblk) blockoff[t] = src[t] - v;   // exclusive
    if (t == 0) row_ptr[m] = nnz;
}

// S3: per-block LDS scan of its chunk + block offset -> row_ptr & cursor.
__global__ __launch_bounds__(256) void scan_apply_kernel(
    const int* __restrict__ counts, const int* __restrict__ blockoff,
    int* __restrict__ row_ptr, int* __restrict__ cursor, int m) {
    __shared__ int bufA[256];
    __shared__ int bufB[256];
    const int t = threadIdx.x;
    const int g = blockIdx.x * SCAN_CHUNK + t * 4;
    int c0 = 0, c1 = 0, c2 = 0, c3 = 0;
    if (g + 3 < m) {
        const int4 c = *(const int4*)&counts[g];
        c0 = c.x; c1 = c.y; c2 = c.z; c3 = c.w;
    } else {
        if (g < m)     c0 = counts[g];
        if (g + 1 < m) c1 = counts[g + 1];
        if (g + 2 < m) c2 = counts[g + 2];
    }
    const int s = c0 + c1 + c2 + c3;
    bufA[t] = s;
    __syncthreads();
    int* src = bufA;
    int* dst = bufB;
    for (int off = 1; off < 256; off <<= 1) {
        int x = src[t];
        if (t >= off) x += src[t - off];
        dst[t] = x;
        __syncthreads();
        int* tmp = src; src = dst; dst = tmp;
    }
    const int base = src[t] - s + blockoff[blockIdx.x];
    const int p0 = base, p1 = p0 + c0, p2 = p1 + c1, p3 = p2 + c2;
    if (g + 3 < m) {
        const int4 pq = make_int4(p0, p1, p2, p3);
        *(int4*)&row_ptr[g] = pq;
        *(int4*)&cursor[g]  = pq;
    } else {
        if (g < m)     { row_ptr[g]     = p0; cursor[g]     = p0; }
        if (g + 1 < m) { row_ptr[g + 1] = p1; cursor[g + 1] = p1; }
        if (g + 2 < m) { row_ptr[g + 2] = p2; cursor[g + 2] = p2; }
    }
}

// Counting sort: coalesced reads of indices + 4 value planes; ONE uint4
// scattered store per edge: {col, bf16(v0)|bf16(v1)<<16, bf16(v2)|bf16(v3)<<16, 0}.
__global__ void permute_pack_kernel(const int* __restrict__ indices,
                                    const float* __restrict__ values,
                                    int* __restrict__ cursor,
                                    uint4* __restrict__ edges, int nnz) {
    int i = blockIdx.x * blockDim.x + threadIdx.x;
    const int stride = gridDim.x * blockDim.x;
    for (; i < nnz; i += stride) {
        const int r = indices[i];
        const int c = indices[nnz + i];
        const float v0 = values[i];
        const float v1 = values[(size_t)nnz + i];
        const float v2 = values[2 * (size_t)nnz + i];
        const float v3 = values[3 * (size_t)nnz + i];
        uint4 e;
        e.x = (unsigned)c;
        e.y = f2bf(v0) | (f2bf(v1) << 16);
        e.z = f2bf(v2) | (f2bf(v3) << 16);
        e.w = 0;
        const int pos = atomicAdd(&cursor[r], 1);
        edges[pos] = e;
    }
}

// ---------- main SpMM (bf16 gather, packed edges) ----------
// One wave per row. lane -> (k = lane>>4, f0 = (lane&15)*4).
// Per edge: one sequential uint4 (col+vals) + one 512B-chunk b16 gather.
__global__ __launch_bounds__(256) void spmm_csr_bf16_kernel(
    const int* __restrict__ row_ptr, const uint4* __restrict__ edges,
    const unsigned short* __restrict__ b16, float* __restrict__ out, int m) {
    const int lane = threadIdx.x & 63;
    const int wave = blockIdx.x * (blockDim.x >> 6) + (threadIdx.x >> 6);
    if (wave >= m) return;
    const int row   = wave;
    const int start = row_ptr[row];
    const int end   = row_ptr[row + 1];

    const int k  = lane >> 4;
    const int f0 = (lane & 15) * 4;
    const bool khi = (k & 2) != 0;   // use .z word
    const bool kod = (k & 1) != 0;   // use high half
    const unsigned short* __restrict__ bk = b16 + k * 64 + f0;  // + c*256/edge

#define BF(u) __uint_as_float((unsigned)(u) << 16)
#define VSEL(e) __uint_as_float(kod ? ((khi ? e.z : e.y) & 0xFFFF0000u) \
                                    : ((khi ? e.z : e.y) << 16))
    float4 acc = make_float4(0.f, 0.f, 0.f, 0.f);
    int j = start;
    for (; j + 3 < end; j += 4) {
        const uint4 e0 = edges[j];
        const uint4 e1 = edges[j + 1];
        const uint4 e2 = edges[j + 2];
        const uint4 e3 = edges[j + 3];
        const ushort4 u0 = *(const ushort4*)(bk + (size_t)e0.x * 256);
        const ushort4 u1 = *(const ushort4*)(bk + (size_t)e1.x * 256);
        const ushort4 u2 = *(const ushort4*)(bk + (size_t)e2.x * 256);
        const ushort4 u3 = *(const ushort4*)(bk + (size_t)e3.x * 256);
        const float v0 = VSEL(e0);
        const float v1 = VSEL(e1);
        const float v2 = VSEL(e2);
        const float v3 = VSEL(e3);
        acc.x += v0 * BF(u0.x) + v1 * BF(u1.x) + v2 * BF(u2.x) + v3 * BF(u3.x);
        acc.y += v0 * BF(u0.y) + v1 * BF(u1.y) + v2 * BF(u2.y) + v3 * BF(u3.y);
        acc.z += v0 * BF(u0.z) + v1 * BF(u1.z) + v2 * BF(u2.z) + v3 * BF(u3.z);
        acc.w += v0 * BF(u0.w) + v1 * BF(u1.w) + v2 * BF(u2.w) + v3 * BF(u3.w);
    }
    for (; j < end; ++j) {
        const uint4 e = edges[j];
        const ushort4 u = *(const ushort4*)(bk + (size_t)e.x * 256);
        const float v = VSEL(e);
        acc.x += v * BF(u.x);
        acc.y += v * BF(u.y);
        acc.z += v * BF(u.z);
        acc.w += v * BF(u.w);
    }
#undef VSEL
#undef BF
    const size_t bm = (size_t)m * FEAT;
    *(float4*)(out + (size_t)k * bm + (size_t)row * FEAT + f0) = acc;
}

// ---------- fallback (round-1 atomic version) ----------
__global__ __launch_bounds__(256) void spmm_atomic_kernel(
    const int* __restrict__ indices, const float* __restrict__ values,
    const float* __restrict__ b, float* __restrict__ out,
    int nnz, int m, int batch, int ntasks) {
    const int lane = threadIdx.x & 63;
    const int waves_per_block = blockDim.x >> 6;
    const int nwaves = gridDim.x * waves_per_block;
    int wave = blockIdx.x * waves_per_block + (threadIdx.x >> 6);
    for (int task = wave; task < ntasks; task += nwaves) {
        const int e = task / batch;
        const int k = task - e * batch;
        const int row = indices[e];
        const int col = indices[nnz + e];
        const float v = values[(size_t)k * nnz + e];
        const float contrib = v * b[((size_t)k * m + col) * FEAT + lane];
        unsafeAtomicAdd(&out[((size_t)k * m + row) * FEAT + lane], contrib);
    }
}

static inline uintptr_t align16(uintptr_t p) { return (p + 15) & ~(uintptr_t)15; }

extern "C" void kernel_launch(void* const* d_in, const int* in_sizes, int n_in,
                              void* d_out, int out_size, void* d_ws, size_t ws_size,
                              hipStream_t stream) {
    const int* indices  = (const int*)d_in[0];    // [2, nnz]
    const float* values = (const float*)d_in[1];  // [batch, nnz]
    const float* b      = (const float*)d_in[4];  // [batch, m, FEAT]
    float* out          = (float*)d_out;

    const int nnz   = in_sizes[0] / 2;
    const int batch = in_sizes[1] / nnz;
    const int m     = out_size / (batch * FEAT);
    const int nblk  = (m + SCAN_CHUNK - 1) / SCAN_CHUNK;

    // ws layout, each array 16B-aligned:
    uintptr_t p = (uintptr_t)d_ws;
    int* counts      = (int*)align16(p);             p = (uintptr_t)(counts + m);
    int* row_ptr     = (int*)align16(p);             p = (uintptr_t)(row_ptr + m + 1);
    int* cursor      = (int*)align16(p);             p = (uintptr_t)(cursor + m);
    int* blocksum    = (int*)align16(p);             p = (uintptr_t)(blocksum + nblk);
    int* blockoff    = (int*)align16(p);             p = (uintptr_t)(blockoff + nblk);
    uint4* edges     = (uint4*)align16(p);           p = (uintptr_t)(edges + nnz);
    unsigned short* b16 = (unsigned short*)align16(p);
    p = (uintptr_t)(b16 + (size_t)m * 4 * FEAT);
    const size_t need = p - (uintptr_t)d_ws;

    if (batch != 4 || nblk > 256 || ws_size < need) {
        hipMemsetAsync(d_out, 0, (size_t)out_size * sizeof(float), stream);
        spmm_atomic_kernel<<<2048, 256, 0, stream>>>(indices, values, b, out,
                                                     nnz, m, batch, nnz * batch);
        return;
    }

    hipMemsetAsync(counts, 0, (size_t)m * sizeof(int), stream);
    // b has 4*m*16 = m*FEAT float4s total (FIX: R8 used m*16, leaving 3/4 of
    // b16 poisoned).
    const int tblocks = (m * FEAT + 255) / 256;
    hist_transform_kernel<<<HIST_BLOCKS + tblocks, 256, 0, stream>>>(
        indices, counts, nnz, b, b16, m);
    scan_partial_kernel<<<nblk, 256, 0, stream>>>(counts, blocksum, m);
    scan_block_kernel<<<1, 256, 0, stream>>>(blocksum, blockoff, nblk,
                                             row_ptr, m, nnz);
    scan_apply_kernel<<<nblk, 256, 0, stream>>>(counts, blockoff,
                                                row_ptr, cursor, m);
    permute_pack_kernel<<<PERM_BLOCKS, 256, 0, stream>>>(indices, values,
                                                         cursor, edges, nnz);

    const int waves_per_block = 4;  // 256 threads
    const int grid = (m + waves_per_block - 1) / waves_per_block;
    spmm_csr_bf16_kernel<<<grid, 256, 0, stream>>>(row_ptr, edges, b16,
                                                   out, m);
}